// Round 3
// baseline (204.975 us; speedup 1.0000x reference)
//
#include <hip/hip_runtime.h>
#include <math.h>

#define EPSC 1e-6f
#define THETAC 1e-3f
#define C1C 1e-4f
#define C2C 9e-4f
#define DEN_EPS 1e-12f

constexpr int Bn = 4, Cn = 16, Hn = 512, Wn = 512;
constexpr int HW = Hn * Wn;          // 262144 = 2^18
constexpr int NP = Bn * HW;          // 1048576
constexpr int TS = 32, RAD = 5, K = 11;
constexpr int HALO = TS + 2 * RAD;   // 42 (single-halo, k_ssim)
constexpr int PITCH = 43;
constexpr int HP = 33;
constexpr int ASZ = HALO * PITCH;    // 1806
constexpr int HSZ = HALO * HP;       // 1386
constexpr int tiles_x = Wn / TS;     // 16
constexpr int NT = tiles_x * (Hn / TS); // 256

// double-halo geometry for fused a/b + output kernel
constexpr int H2 = TS + 4 * RAD;     // 52
constexpr int P2 = H2 + 1;           // 53
constexpr int A2 = H2 * P2;          // 2756
constexpr int M1 = TS + 2 * RAD;     // 42
constexpr int MP = M1 + 1;           // 43
constexpr int HS1 = H2 * MP;         // 2236

__device__ __forceinline__ int refl(int i, int n) {
    if (i < 0) i = -i;
    if (i >= n) i = 2 * n - 2 - i;
    return i;
}

__device__ __forceinline__ int swz_tile(int x) { return (x & 7) * (NT / 8) + (x >> 3); }

// ---------------- K1: Xs = mean over channels (float4) ----------------
__global__ void __launch_bounds__(256) k_xs(const float* __restrict__ X, float* __restrict__ Xs) {
    constexpr int NP4 = NP / 4, HW4 = HW / 4;
    int i = blockIdx.x * 256 + threadIdx.x;
    if (i >= NP4) return;
    int b = i / HW4, off = i - b * HW4;
    const float4* xp = (const float4*)(X + (size_t)b * Cn * HW) + off;
    float4 s = make_float4(0.f, 0.f, 0.f, 0.f);
#pragma unroll
    for (int c = 0; c < Cn; ++c) {
        float4 v = xp[(size_t)c * HW4];
        s.x += v.x; s.y += v.y; s.z += v.z; s.w += v.w;
    }
    const float sc = 1.0f / Cn;
    s.x *= sc; s.y *= sc; s.z *= sc; s.w *= sc;
    ((float4*)Xs)[i] = s;
}

// ---------------- K2: chi + per-block {sum,min} ----------------
__global__ void __launch_bounds__(256) k_chi(const float* __restrict__ G, float* __restrict__ chi,
                      float* __restrict__ psum, float* __restrict__ pmin) {
    __shared__ float ssum[256], smin[256];
    int t = threadIdx.x;
    int base = blockIdx.x * 1024;
    float ls = 0.f, lm = 1e30f;
#pragma unroll
    for (int k = 0; k < 4; ++k) {
        int p = base + t + k * 256;
        int off = p & (HW - 1);
        int y = off / Wn, x = off & (Wn - 1);
        float g = G[p];
        float gx = (x < Wn - 1) ? G[p + 1] - g : 0.f;
        float gy = (y < Hn - 1) ? G[p + Wn] - g : 0.f;
        float c = sqrtf(gx * gx + gy * gy + EPSC);
        chi[p] = c;
        ls += c;
        lm = fminf(lm, c);
    }
    ssum[t] = ls; smin[t] = lm;
    __syncthreads();
    for (int s = 128; s > 0; s >>= 1) {
        if (t < s) { ssum[t] += ssum[t + s]; smin[t] = fminf(smin[t], smin[t + s]); }
        __syncthreads();
    }
    if (t == 0) { psum[blockIdx.x] = ssum[0]; pmin[blockIdx.x] = smin[0]; }
}

__global__ void __launch_bounds__(256) k_chired(const float* __restrict__ psum, const float* __restrict__ pmin,
                         float* __restrict__ sc) {
    __shared__ float ssum[256], smin[256];
    int t = threadIdx.x, b = blockIdx.x;
    ssum[t] = psum[b * 256 + t];
    smin[t] = pmin[b * 256 + t];
    __syncthreads();
    for (int s = 128; s > 0; s >>= 1) {
        if (t < s) { ssum[t] += ssum[t + s]; smin[t] = fminf(smin[t], smin[t + s]); }
        __syncthreads();
    }
    if (t == 0) {
        float mu = ssum[0] / (float)HW;
        sc[b] = mu;
        sc[4 + b] = fmaxf(mu - smin[0], EPSC);
    }
}

// hbox helpers for k_ssim (single-halo geometry)
__device__ __forceinline__ void hbox(const float* sp, float* hs, int t, int npl) {
    if (t < 84 * npl) {
        int pl = t / 84, rem = t - pl * 84;
        int y = rem >> 1, xh = (rem & 1) << 4;
        const float* src = sp + pl * ASZ + y * PITCH + xh;
        float* hd = hs + pl * HSZ + y * HP + xh;
        float s = 0.f;
#pragma unroll
        for (int dx = 0; dx < K; ++dx) s += src[dx];
        hd[0] = s;
#pragma unroll
        for (int j = 1; j < 16; ++j) { s += src[j + K - 1] - src[j - 1]; hd[j] = s; }
    }
}

__device__ __forceinline__ void vbox(const float* hs, int x, int r0, float m[4]) {
    const float inv_area = 1.f / (float)(K * K);
    int base = r0 * HP + x;
    float s = 0.f;
#pragma unroll
    for (int dy = 0; dy < K; ++dy) s += hs[base + dy * HP];
    m[0] = s * inv_area;
#pragma unroll
    for (int j = 1; j < 4; ++j) {
        s += hs[base + (j + K - 1) * HP] - hs[base + (j - 1) * HP];
        m[j] = s * inv_area;
    }
}

// ---------------- K3: merged ssim r=5 & r=1 + plane outputs + reductions ----------------
__global__ void __launch_bounds__(256) k_ssim(
        const float* __restrict__ Xs, const float* __restrict__ G,
        float* __restrict__ muG, float* __restrict__ varGr, float* __restrict__ taur,
        float* __restrict__ chig, float* __restrict__ nu,
        float* __restrict__ ps1, float* __restrict__ ps2) {
    __shared__ float arrs[5 * ASZ];
    __shared__ float hs[2 * HSZ];
    __shared__ float red1[256], red2[256];
    int t = threadIdx.x;
    int b = blockIdx.y;
    int tile = swz_tile(blockIdx.x);
    int tx0 = (tile % tiles_x) * TS, ty0 = (tile / tiles_x) * TS;
    const float* Xp = Xs + (size_t)b * HW;
    const float* Gp = G + (size_t)b * HW;
    for (int i = t; i < HALO * HALO; i += 256) {
        int ly = i / HALO, lx = i - ly * HALO;
        int gy = refl(ty0 - RAD + ly, Hn), gx = refl(tx0 - RAD + lx, Wn);
        float vx = Xp[gy * Wn + gx], vg = Gp[gy * Wn + gx];
        int o = ly * PITCH + lx;
        arrs[o] = vx;
        arrs[ASZ + o] = vg;
        arrs[2 * ASZ + o] = vx * vx;
        arrs[3 * ASZ + o] = vg * vg;
        arrs[4 * ASZ + o] = vx * vg;
    }
    __syncthreads();

    int x = t & 31, g = t >> 5, r0 = g * 4;
    float acc[5][4];
#pragma unroll
    for (int round = 0; round < 3; ++round) {
        const int npl = (round < 2) ? 2 : 1;
        hbox(arrs + 2 * round * ASZ, hs, t, npl);
        __syncthreads();
#pragma unroll
        for (int pl = 0; pl < npl; ++pl) vbox(hs + pl * HSZ, x, r0, acc[2 * round + pl]);
        __syncthreads();
    }

    float m1[5][4];
#pragma unroll
    for (int p = 0; p < 5; ++p) {
        float h3[6];
#pragma unroll
        for (int j = 0; j < 6; ++j) {
            int bb = p * ASZ + (r0 + 4 + j) * PITCH + (x + 4);
            h3[j] = arrs[bb] + arrs[bb + 1] + arrs[bb + 2];
        }
#pragma unroll
        for (int j = 0; j < 4; ++j)
            m1[p][j] = (h3[j] + h3[j + 1] + h3[j + 2]) * (1.f / 9.f);
    }

    float l1 = 0.f, l2 = 0.f;
#pragma unroll
    for (int j = 0; j < 4; ++j) {
        float mux = acc[0][j], mug = acc[1][j], mxx = acc[2][j], mgg = acc[3][j], mxy = acc[4][j];
        float sx2 = fmaxf(mxx - mux * mux, 0.f);
        float sg2 = fmaxf(mgg - mug * mug, 0.f);
        float sxy = mxy - mux * mug;
        float num = (2.f * mux * mug + C1C) * (2.f * sxy + C2C);
        float den = (mux * mux + mug * mug + C1C) * (sx2 + sg2 + C2C);
        float tr_ = fminf(fmaxf((num / (den + DEN_EPS) + 1.f) * 0.5f, 0.f), 1.f);

        float n0 = m1[0][j], n1 = m1[1][j], n2 = m1[2][j], n3 = m1[3][j], n4 = m1[4][j];
        float sx21 = fmaxf(n2 - n0 * n0, 0.f);
        float sg21 = fmaxf(n3 - n1 * n1, 0.f);
        float sxy1 = n4 - n0 * n1;
        float num1 = (2.f * n0 * n1 + C1C) * (2.f * sxy1 + C2C);
        float den1 = (n0 * n0 + n1 * n1 + C1C) * (sx21 + sg21 + C2C);
        float t1_ = fminf(fmaxf((num1 / (den1 + DEN_EPS) + 1.f) * 0.5f, 0.f), 1.f);

        float chig_ = sqrtf(sg21 + EPSC) * sqrtf(sg2 + EPSC);
        float nu_ = fmaxf(t1_ * tr_, 0.f);
        int gp = b * HW + (ty0 + r0 + j) * Wn + (tx0 + x);
        muG[gp] = mug;
        varGr[gp] = sg2;
        taur[gp] = tr_;
        chig[gp] = chig_;
        nu[gp] = nu_;
        l1 += 1.f / (chig_ + EPSC);
        l2 += 1.f / (nu_ + THETAC);
    }
    red1[t] = l1; red2[t] = l2;
    __syncthreads();
    for (int s = 128; s > 0; s >>= 1) {
        if (t < s) { red1[t] += red1[t + s]; red2[t] += red2[t + s]; }
        __syncthreads();
    }
    if (t == 0) {
        ps1[b * NT + blockIdx.x] = red1[0];
        ps2[b * NT + blockIdx.x] = red2[0];
    }
}

__global__ void __launch_bounds__(256) k_nured(const float* __restrict__ s1, const float* __restrict__ s2,
                        float* __restrict__ sc) {
    __shared__ float a1[256], a2[256];
    int t = threadIdx.x, b = blockIdx.x;
    a1[t] = s1[b * 256 + t];
    a2[t] = s2[b * 256 + t];
    __syncthreads();
    for (int s = 128; s > 0; s >>= 1) {
        if (t < s) { a1[t] += a1[t + s]; a2[t] += a2[t + s]; }
        __syncthreads();
    }
    if (t == 0) {
        sc[8 + b] = a1[0] / (float)HW;
        sc[12 + b] = a2[0] / (float)HW;
    }
}

// ---------------- K4: per-pixel packed (P, D, muG) plane ----------------
__global__ void __launch_bounds__(256) k_pd(
        const float* __restrict__ chi, const float* __restrict__ chig,
        const float* __restrict__ nu, const float* __restrict__ taur,
        const float* __restrict__ vr, const float* __restrict__ muG,
        const float* __restrict__ sc, float4* __restrict__ PDM) {
    int p = blockIdx.x * 256 + threadIdx.x;
    if (p >= NP) return;
    int b = p >> 18;
    float mu = sc[b], eta = sc[4 + b], imc = sc[8 + b], imn = sc[12 + b];
    float gamma = 1.f / (1.f + expf(-eta * (chi[p] - mu)));
    float GG = (chig[p] + EPSC) * imc;
    float w_e = 1.0f / (GG + EPSC);                 // LAM = 1
    float GS = (nu[p] + THETAC) * imn;
    float w_s = gamma / (GS + EPSC);
    float P = w_e * gamma + w_s * taur[p];
    float D = vr[p] + EPSC + w_e + w_s + EPSC;
    PDM[p] = make_float4(P, D, muG[p], 0.f);
}

// ---------------- K5: fused a,b + out (double halo, radius 10) ----------------
__global__ void __launch_bounds__(256) k_about(
        const float* __restrict__ X, const float* __restrict__ G,
        const float4* __restrict__ PDM, float* __restrict__ out) {
    __shared__ float sg[A2], s0[A2], s1[A2];   // G halo; X -> a; X*G -> b
    __shared__ float h0[HS1], h1[HS1];
    int t = threadIdx.x;
    int pc = blockIdx.y, b = pc >> 4;
    int tile = swz_tile(blockIdx.x);
    int tx0 = (tile & 15) * TS, ty0 = (tile >> 4) * TS;
    const float* Xp = X + (size_t)pc * HW;
    const float* Gp = G + (size_t)b * HW;

    // A: load 52x52 halos of X, G; form X*G
    for (int i = t; i < H2 * H2; i += 256) {
        int ly = i / H2, lx = i - ly * H2;
        int gy = refl(ty0 - 10 + ly, Hn), gx = refl(tx0 - 10 + lx, Wn);
        float vg = Gp[gy * Wn + gx], vx = Xp[gy * Wn + gx];
        int o = ly * P2 + lx;
        sg[o] = vg; s0[o] = vx; s1[o] = vx * vg;
    }
    __syncthreads();

    // B: hbox11: 52 rows -> width 42, planes X, XG (208 threads, 21-wide halves)
    if (t < 208) {
        int pl = t / 104, rem = t - pl * 104;
        int y = rem >> 1, x0 = (rem & 1) * 21;
        const float* src = (pl ? s1 : s0) + y * P2 + x0;
        float* dst = (pl ? h1 : h0) + y * MP + x0;
        float s = 0.f;
#pragma unroll
        for (int dx = 0; dx < K; ++dx) s += src[dx];
        dst[0] = s;
#pragma unroll
        for (int j = 1; j < 21; ++j) { s += src[j + 10] - src[j - 1]; dst[j] = s; }
    }
    __syncthreads();

    // C: vbox11 -> mx, mxg on 42x42; form a,b; store into s0/s1 (pitch 43)
    if (t < 252) {
        int x = t % 42, g = t / 42, r0 = g * 7;
        int base = r0 * MP + x;
        float sx = 0.f, sxg = 0.f;
#pragma unroll
        for (int dy = 0; dy < K; ++dy) { sx += h0[base + dy * MP]; sxg += h1[base + dy * MP]; }
        const float inv_area = 1.f / 121.f;
        const float4* Pp = PDM + (size_t)b * HW;
#pragma unroll
        for (int j = 0; j < 7; ++j) {
            if (j) {
                sx += h0[base + (j + 10) * MP] - h0[base + (j - 1) * MP];
                sxg += h1[base + (j + 10) * MP] - h1[base + (j - 1) * MP];
            }
            float mx = sx * inv_area, mxg = sxg * inv_area;
            int py = refl(ty0 - 5 + r0 + j, Hn), px = refl(tx0 - 5 + x, Wn);
            float4 pdm = Pp[py * Wn + px];
            float a = (mxg - pdm.z * mx + pdm.x) / pdm.y;
            s0[(r0 + j) * MP + x] = a;
            s1[(r0 + j) * MP + x] = mx - a * pdm.z;
        }
    }
    __syncthreads();

    // D: hbox11 on a,b: 42 rows -> width 32 (168 threads, 16-wide halves)
    if (t < 168) {
        int pl = t / 84, rem = t - pl * 84;
        int y = rem >> 1, x0 = (rem & 1) * 16;
        const float* src = (pl ? s1 : s0) + y * MP + x0;
        float* dst = (pl ? h1 : h0) + y * HP + x0;
        float s = 0.f;
#pragma unroll
        for (int dx = 0; dx < K; ++dx) s += src[dx];
        dst[0] = s;
#pragma unroll
        for (int j = 1; j < 16; ++j) { s += src[j + 10] - src[j - 1]; dst[j] = s; }
    }
    __syncthreads();

    // E: vbox11 -> ma, mb on 32x32; out = ma*G + mb
    {
        int x = t & 31, g = t >> 5, r0 = g * 4;
        int base = r0 * HP + x;
        float sa = 0.f, sb = 0.f;
#pragma unroll
        for (int dy = 0; dy < K; ++dy) { sa += h0[base + dy * HP]; sb += h1[base + dy * HP]; }
        float* op = out + (size_t)pc * HW;
        const float inv_area = 1.f / 121.f;
#pragma unroll
        for (int j = 0; j < 4; ++j) {
            if (j) {
                sa += h0[base + (j + 10) * HP] - h0[base + (j - 1) * HP];
                sb += h1[base + (j + 10) * HP] - h1[base + (j - 1) * HP];
            }
            int row = r0 + j;
            float ma = sa * inv_area, mb = sb * inv_area;
            op[(ty0 + row) * Wn + tx0 + x] = ma * sg[(row + 10) * P2 + x + 10] + mb;
        }
    }
}

extern "C" void kernel_launch(void* const* d_in, const int* in_sizes, int n_in,
                              void* d_out, int out_size, void* d_ws, size_t ws_size,
                              hipStream_t stream) {
    const float* X = (const float*)d_in[0];
    const float* G = (const float*)d_in[1];
    float* out = (float*)d_out;
    float* ws = (float*)d_ws;

    float* Xs   = ws + 0 * (size_t)NP;
    float* chi  = ws + 1 * (size_t)NP;
    float* taur = ws + 2 * (size_t)NP;
    float* vr   = ws + 3 * (size_t)NP;
    float* muG  = ws + 4 * (size_t)NP;
    float* chig = ws + 5 * (size_t)NP;
    float* nu   = ws + 6 * (size_t)NP;
    float4* PDM = (float4*)(ws + 7 * (size_t)NP);   // 4*NP floats
    float* psum = ws + 11 * (size_t)NP;
    float* pmin = psum + 1024;
    float* ps1  = pmin + 1024;
    float* ps2  = ps1 + 1024;
    float* sc   = ps2 + 1024;   // 16 scalars

    dim3 blk(256);
    k_xs<<<(NP / 4) / 256, blk, 0, stream>>>(X, Xs);
    k_chi<<<NP / 1024, blk, 0, stream>>>(G, chi, psum, pmin);
    k_chired<<<4, blk, 0, stream>>>(psum, pmin, sc);

    dim3 gplane(NT, Bn);
    k_ssim<<<gplane, blk, 0, stream>>>(Xs, G, muG, vr, taur, chig, nu, ps1, ps2);
    k_nured<<<4, blk, 0, stream>>>(ps1, ps2, sc);
    k_pd<<<NP / 256, blk, 0, stream>>>(chi, chig, nu, taur, vr, muG, sc, PDM);

    dim3 gchan(NT, Bn * Cn);
    k_about<<<gchan, blk, 0, stream>>>(X, G, PDM, out);
}

// Round 4
// 159.992 us; speedup vs baseline: 1.2812x; 1.2812x over previous
//
#include <hip/hip_runtime.h>
#include <math.h>

#define EPSC 1e-6f
#define THETAC 1e-3f
#define C1C 1e-4f
#define C2C 9e-4f
#define DEN_EPS 1e-12f

constexpr int Bn = 4, Cn = 16, Hn = 512, Wn = 512;
constexpr int HW = Hn * Wn;          // 262144 = 2^18
constexpr int NP = Bn * HW;          // 1048576
constexpr int TS = 32, RAD = 5, K = 11;
constexpr int HALO = TS + 2 * RAD;   // 42
constexpr int PITCH = 43;            // k_ssim halo pitch
constexpr int HP = 33;               // horizontal-sum pitch
constexpr int ASZ = HALO * PITCH;    // 1806 (k_ssim)
constexpr int HSZ = HALO * HP;       // 1386
constexpr int tiles_x = Wn / TS;     // 16
constexpr int NT = tiles_x * (Hn / TS); // 256

// 48-wide aligned window geometry for channel-pass tiles
constexpr int W2 = 48;               // window width (aligned, covers halo [-5,36] at offset 3)
constexpr int P49 = 49;              // padded pitch
constexpr int ASZ2 = HALO * P49;     // 2058

__device__ __forceinline__ int refl(int i, int n) {
    if (i < 0) i = -i;
    if (i >= n) i = 2 * n - 2 - i;
    return i;
}

__device__ __forceinline__ int swz_tile(int x) { return (x & 7) * (NT / 8) + (x >> 3); }

__device__ __forceinline__ void vbox(const float* hs, int x, int r0, float m[4]) {
    const float inv_area = 1.f / (float)(K * K);
    int base = r0 * HP + x;
    float s = 0.f;
#pragma unroll
    for (int dy = 0; dy < K; ++dy) s += hs[base + dy * HP];
    m[0] = s * inv_area;
#pragma unroll
    for (int j = 1; j < 4; ++j) {
        s += hs[base + (j + K - 1) * HP] - hs[base + (j - 1) * HP];
        m[j] = s * inv_area;
    }
}

// hbox on 48-wide window (src offset +3), 16-wide output chunks
__device__ __forceinline__ void hbox48(const float* s0, const float* s1,
                                       float* h0, float* h1, int t) {
    if (t < 168) {
        int pl = t / 84, rem = t - pl * 84;
        int y = rem >> 1, xh = (rem & 1) << 4;
        const float* src = (pl ? s1 : s0) + y * P49 + xh + 3;
        float* hd = (pl ? h1 : h0) + y * HP + xh;
        float s = 0.f;
#pragma unroll
        for (int dx = 0; dx < K; ++dx) s += src[dx];
        hd[0] = s;
#pragma unroll
        for (int j = 1; j < 16; ++j) { s += src[j + 10] - src[j - 1]; hd[j] = s; }
    }
}

// ---------------- K1: merged Xs (channel mean) + chi (+partial reductions) ----------------
__global__ void __launch_bounds__(256) k_xschi(
        const float* __restrict__ X, const float* __restrict__ G,
        float* __restrict__ Xs, float* __restrict__ chi,
        float* __restrict__ psum, float* __restrict__ pmin) {
    int t = threadIdx.x;
    if (blockIdx.x < 1024) {
        constexpr int HW4 = HW / 4;
        int i = blockIdx.x * 256 + t;
        int b = i / HW4, off = i - b * HW4;
        const float4* xp = (const float4*)(X + (size_t)b * Cn * HW) + off;
        float4 s = make_float4(0.f, 0.f, 0.f, 0.f);
#pragma unroll
        for (int c = 0; c < Cn; ++c) {
            float4 v = xp[(size_t)c * HW4];
            s.x += v.x; s.y += v.y; s.z += v.z; s.w += v.w;
        }
        const float sc = 1.0f / Cn;
        s.x *= sc; s.y *= sc; s.z *= sc; s.w *= sc;
        ((float4*)Xs)[i] = s;
        return;
    }
    __shared__ float ssum[256], smin[256];
    int bid = blockIdx.x - 1024;
    int base = bid * 1024;
    float ls = 0.f, lm = 1e30f;
#pragma unroll
    for (int k = 0; k < 4; ++k) {
        int p = base + t + k * 256;
        int off = p & (HW - 1);
        int y = off / Wn, x = off & (Wn - 1);
        float g = G[p];
        float gx = (x < Wn - 1) ? G[p + 1] - g : 0.f;
        float gy = (y < Hn - 1) ? G[p + Wn] - g : 0.f;
        float c = sqrtf(gx * gx + gy * gy + EPSC);
        chi[p] = c;
        ls += c;
        lm = fminf(lm, c);
    }
    ssum[t] = ls; smin[t] = lm;
    __syncthreads();
    for (int s = 128; s > 0; s >>= 1) {
        if (t < s) { ssum[t] += ssum[t + s]; smin[t] = fminf(smin[t], smin[t + s]); }
        __syncthreads();
    }
    if (t == 0) { psum[bid] = ssum[0]; pmin[bid] = smin[0]; }
}

// ---------------- K3: merged ssim r=5 & r=1 + plane outputs + reductions ----------------
__global__ void __launch_bounds__(256) k_ssim(
        const float* __restrict__ Xs, const float* __restrict__ G,
        float* __restrict__ muG, float* __restrict__ varGr, float* __restrict__ taur,
        float* __restrict__ chig, float* __restrict__ nu,
        float* __restrict__ ps1, float* __restrict__ ps2) {
    __shared__ float arrs[5 * ASZ];
    __shared__ float hs[2 * HSZ];
    __shared__ float red1[256], red2[256];
    int t = threadIdx.x;
    int b = blockIdx.y;
    int tile = swz_tile(blockIdx.x);
    int tx0 = (tile % tiles_x) * TS, ty0 = (tile / tiles_x) * TS;
    const float* Xp = Xs + (size_t)b * HW;
    const float* Gp = G + (size_t)b * HW;
    for (int i = t; i < HALO * HALO; i += 256) {
        int ly = i / HALO, lx = i - ly * HALO;
        int gy = refl(ty0 - RAD + ly, Hn), gx = refl(tx0 - RAD + lx, Wn);
        float vx = Xp[gy * Wn + gx], vg = Gp[gy * Wn + gx];
        int o = ly * PITCH + lx;
        arrs[o] = vx;
        arrs[ASZ + o] = vg;
        arrs[2 * ASZ + o] = vx * vx;
        arrs[3 * ASZ + o] = vg * vg;
        arrs[4 * ASZ + o] = vx * vg;
    }
    __syncthreads();

    int x = t & 31, g = t >> 5, r0 = g * 4;
    float acc[5][4];
#pragma unroll
    for (int round = 0; round < 3; ++round) {
        const int npl = (round < 2) ? 2 : 1;
        // hbox on pitch-43 halo arrays
        if (t < 84 * npl) {
            int pl = t / 84, rem = t - pl * 84;
            int y = rem >> 1, xh = (rem & 1) << 4;
            const float* src = arrs + (2 * round + pl) * ASZ + y * PITCH + xh;
            float* hd = hs + pl * HSZ + y * HP + xh;
            float s = 0.f;
#pragma unroll
            for (int dx = 0; dx < K; ++dx) s += src[dx];
            hd[0] = s;
#pragma unroll
            for (int j = 1; j < 16; ++j) { s += src[j + K - 1] - src[j - 1]; hd[j] = s; }
        }
        __syncthreads();
#pragma unroll
        for (int pl = 0; pl < npl; ++pl) if (pl < npl) vbox(hs + pl * HSZ, x, r0, acc[2 * round + pl]);
        __syncthreads();
    }

    float m1[5][4];
#pragma unroll
    for (int p = 0; p < 5; ++p) {
        float h3[6];
#pragma unroll
        for (int j = 0; j < 6; ++j) {
            int bb = p * ASZ + (r0 + 4 + j) * PITCH + (x + 4);
            h3[j] = arrs[bb] + arrs[bb + 1] + arrs[bb + 2];
        }
#pragma unroll
        for (int j = 0; j < 4; ++j)
            m1[p][j] = (h3[j] + h3[j + 1] + h3[j + 2]) * (1.f / 9.f);
    }

    float l1 = 0.f, l2 = 0.f;
#pragma unroll
    for (int j = 0; j < 4; ++j) {
        float mux = acc[0][j], mug = acc[1][j], mxx = acc[2][j], mgg = acc[3][j], mxy = acc[4][j];
        float sx2 = fmaxf(mxx - mux * mux, 0.f);
        float sg2 = fmaxf(mgg - mug * mug, 0.f);
        float sxy = mxy - mux * mug;
        float num = (2.f * mux * mug + C1C) * (2.f * sxy + C2C);
        float den = (mux * mux + mug * mug + C1C) * (sx2 + sg2 + C2C);
        float tr_ = fminf(fmaxf((num / (den + DEN_EPS) + 1.f) * 0.5f, 0.f), 1.f);

        float n0 = m1[0][j], n1 = m1[1][j], n2 = m1[2][j], n3 = m1[3][j], n4 = m1[4][j];
        float sx21 = fmaxf(n2 - n0 * n0, 0.f);
        float sg21 = fmaxf(n3 - n1 * n1, 0.f);
        float sxy1 = n4 - n0 * n1;
        float num1 = (2.f * n0 * n1 + C1C) * (2.f * sxy1 + C2C);
        float den1 = (n0 * n0 + n1 * n1 + C1C) * (sx21 + sg21 + C2C);
        float t1_ = fminf(fmaxf((num1 / (den1 + DEN_EPS) + 1.f) * 0.5f, 0.f), 1.f);

        float chig_ = sqrtf(sg21 + EPSC) * sqrtf(sg2 + EPSC);
        float nu_ = fmaxf(t1_ * tr_, 0.f);
        int gp = b * HW + (ty0 + r0 + j) * Wn + (tx0 + x);
        muG[gp] = mug;
        varGr[gp] = sg2;
        taur[gp] = tr_;
        chig[gp] = chig_;
        nu[gp] = nu_;
        l1 += 1.f / (chig_ + EPSC);
        l2 += 1.f / (nu_ + THETAC);
    }
    red1[t] = l1; red2[t] = l2;
    __syncthreads();
    for (int s = 128; s > 0; s >>= 1) {
        if (t < s) { red1[t] += red1[t + s]; red2[t] += red2[t + s]; }
        __syncthreads();
    }
    if (t == 0) {
        ps1[b * NT + blockIdx.x] = red1[0];
        ps2[b * NT + blockIdx.x] = red2[0];
    }
}

// ---------------- K red: merged chired + nured ----------------
__global__ void __launch_bounds__(256) k_red(
        const float* __restrict__ psum, const float* __restrict__ pmin,
        const float* __restrict__ s1, const float* __restrict__ s2,
        float* __restrict__ sc) {
    __shared__ float a1[256], a2[256];
    int t = threadIdx.x;
    if (blockIdx.x < 4) {
        int b = blockIdx.x;
        a1[t] = psum[b * 256 + t];
        a2[t] = pmin[b * 256 + t];
        __syncthreads();
        for (int s = 128; s > 0; s >>= 1) {
            if (t < s) { a1[t] += a1[t + s]; a2[t] = fminf(a2[t], a2[t + s]); }
            __syncthreads();
        }
        if (t == 0) {
            float mu = a1[0] / (float)HW;
            sc[b] = mu;
            sc[4 + b] = fmaxf(mu - a2[0], EPSC);
        }
    } else {
        int b = blockIdx.x - 4;
        a1[t] = s1[b * 256 + t];
        a2[t] = s2[b * 256 + t];
        __syncthreads();
        for (int s = 128; s > 0; s >>= 1) {
            if (t < s) { a1[t] += a1[t + s]; a2[t] += a2[t + s]; }
            __syncthreads();
        }
        if (t == 0) {
            sc[8 + b] = a1[0] / (float)HW;
            sc[12 + b] = a2[0] / (float)HW;
        }
    }
}

// ---------------- K4: per-pixel packed (P, D, muG) plane, 4-wide ----------------
__global__ void __launch_bounds__(256) k_pd(
        const float* __restrict__ chi, const float* __restrict__ chig,
        const float* __restrict__ nu, const float* __restrict__ taur,
        const float* __restrict__ vr, const float* __restrict__ muG,
        const float* __restrict__ sc, float4* __restrict__ PDM) {
    int i = blockIdx.x * 256 + threadIdx.x;   // i < NP/4
    int p0 = i * 4;
    int b = p0 >> 18;
    float mu = sc[b], eta = sc[4 + b], imc = sc[8 + b], imn = sc[12 + b];
    float4 c4 = ((const float4*)chi)[i];
    float4 cg4 = ((const float4*)chig)[i];
    float4 nu4 = ((const float4*)nu)[i];
    float4 tr4 = ((const float4*)taur)[i];
    float4 vr4 = ((const float4*)vr)[i];
    float4 mg4 = ((const float4*)muG)[i];
    float cc[4] = {c4.x, c4.y, c4.z, c4.w};
    float gg[4] = {cg4.x, cg4.y, cg4.z, cg4.w};
    float nn[4] = {nu4.x, nu4.y, nu4.z, nu4.w};
    float tt[4] = {tr4.x, tr4.y, tr4.z, tr4.w};
    float vv[4] = {vr4.x, vr4.y, vr4.z, vr4.w};
    float mm[4] = {mg4.x, mg4.y, mg4.z, mg4.w};
#pragma unroll
    for (int j = 0; j < 4; ++j) {
        float gamma = 1.f / (1.f + expf(-eta * (cc[j] - mu)));
        float GG = (gg[j] + EPSC) * imc;
        float w_e = 1.0f / (GG + EPSC);
        float GS = (nn[j] + THETAC) * imn;
        float w_s = gamma / (GS + EPSC);
        float P = w_e * gamma + w_s * tt[j];
        float D = vv[j] + EPSC + w_e + w_s + EPSC;
        PDM[p0 + j] = make_float4(P, D, mm[j], 0.f);
    }
}

// ---------------- K5: per-channel a,b (48-window, float4 loads) ----------------
__global__ void __launch_bounds__(256) k_ab(
        const float* __restrict__ X, const float* __restrict__ G,
        const float4* __restrict__ PDM, float2* __restrict__ AB) {
    __shared__ float s0[ASZ2], s1[ASZ2];   // X, X*G (48-wide window, pitch 49)
    __shared__ float h0[HSZ], h1[HSZ];
    int t = threadIdx.x;
    int pc = blockIdx.y, b = pc >> 4;
    int tile = swz_tile(blockIdx.x);
    int tx0 = (tile & 15) * TS, ty0 = (tile >> 4) * TS;
    const float* Xp = X + (size_t)pc * HW;
    const float* Gp = G + (size_t)b * HW;
    bool interior = (tx0 >= 32 && tx0 <= 448 && ty0 >= 32 && ty0 <= 448);
    if (interior) {
        int base = (ty0 - 5) * Wn + (tx0 - 8);
        for (int u = t; u < HALO * 12; u += 256) {     // 504 units
            int ly = u / 12, k = u - ly * 12;
            int gi = base + ly * Wn + 4 * k;
            float4 xv = *(const float4*)(Xp + gi);
            float4 gv = *(const float4*)(Gp + gi);
            int o = ly * P49 + 4 * k;
            s0[o] = xv.x; s0[o + 1] = xv.y; s0[o + 2] = xv.z; s0[o + 3] = xv.w;
            s1[o] = xv.x * gv.x; s1[o + 1] = xv.y * gv.y;
            s1[o + 2] = xv.z * gv.z; s1[o + 3] = xv.w * gv.w;
        }
    } else {
        for (int u = t; u < HALO * W2; u += 256) {     // 2016 units
            int ly = u / W2, l = u - ly * W2;
            int gy = refl(ty0 - 5 + ly, Hn), gx = refl(tx0 - 8 + l, Wn);
            float xv = Xp[gy * Wn + gx], gv = Gp[gy * Wn + gx];
            s0[ly * P49 + l] = xv;
            s1[ly * P49 + l] = xv * gv;
        }
    }
    __syncthreads();
    hbox48(s0, s1, h0, h1, t);
    __syncthreads();
    int x = t & 31, g = t >> 5, r0 = g * 4;
    float mx[4], mxg[4];
    vbox(h0, x, r0, mx);
    vbox(h1, x, r0, mxg);
    const float4* Pp = PDM + (size_t)b * HW;
#pragma unroll
    for (int j = 0; j < 4; ++j) {
        int py = ty0 + r0 + j, px = tx0 + x;
        float4 pdm = Pp[py * Wn + px];
        float a = (mxg[j] - pdm.z * mx[j] + pdm.x) / pdm.y;
        AB[(size_t)pc * HW + py * Wn + px] = make_float2(a, mx[j] - a * pdm.z);
    }
}

// ---------------- K6: out = box11(a)*G + box11(b) ----------------
__global__ void __launch_bounds__(256) k_out(
        const float2* __restrict__ AB, const float* __restrict__ G,
        float* __restrict__ out) {
    __shared__ float s0[ASZ2], s1[ASZ2];   // a, b
    __shared__ float h0[HSZ], h1[HSZ];
    int t = threadIdx.x;
    int pc = blockIdx.y, b = pc >> 4;
    int tile = swz_tile(blockIdx.x);
    int tx0 = (tile & 15) * TS, ty0 = (tile >> 4) * TS;
    const float2* Ap = AB + (size_t)pc * HW;
    bool interior = (tx0 >= 32 && tx0 <= 448 && ty0 >= 32 && ty0 <= 448);
    if (interior) {
        int base = (ty0 - 5) * Wn + (tx0 - 8);
        for (int u = t; u < HALO * 24; u += 256) {     // 1008 units, 2 px each
            int ly = u / 24, m = u - ly * 24;
            float4 v = *(const float4*)((const float*)(Ap + base + ly * Wn) + 4 * m);
            int o = ly * P49 + 2 * m;
            s0[o] = v.x; s0[o + 1] = v.z;
            s1[o] = v.y; s1[o + 1] = v.w;
        }
    } else {
        for (int u = t; u < HALO * W2; u += 256) {
            int ly = u / W2, l = u - ly * W2;
            int gy = refl(ty0 - 5 + ly, Hn), gx = refl(tx0 - 8 + l, Wn);
            float2 v = Ap[gy * Wn + gx];
            s0[ly * P49 + l] = v.x;
            s1[ly * P49 + l] = v.y;
        }
    }
    __syncthreads();
    hbox48(s0, s1, h0, h1, t);
    __syncthreads();
    int x = t & 31, g = t >> 5, r0 = g * 4;
    float ma[4], mb[4];
    vbox(h0, x, r0, ma);
    vbox(h1, x, r0, mb);
    const float* Gp = G + (size_t)b * HW;
    float* op = out + (size_t)pc * HW;
#pragma unroll
    for (int j = 0; j < 4; ++j) {
        int py = ty0 + r0 + j, px = tx0 + x;
        int poff = py * Wn + px;
        op[poff] = ma[j] * Gp[poff] + mb[j];
    }
}

extern "C" void kernel_launch(void* const* d_in, const int* in_sizes, int n_in,
                              void* d_out, int out_size, void* d_ws, size_t ws_size,
                              hipStream_t stream) {
    const float* X = (const float*)d_in[0];
    const float* G = (const float*)d_in[1];
    float* out = (float*)d_out;
    float* ws = (float*)d_ws;

    float* Xs   = ws + 0 * (size_t)NP;
    float* chi  = ws + 1 * (size_t)NP;
    float* taur = ws + 2 * (size_t)NP;
    float* vr   = ws + 3 * (size_t)NP;
    float* muG  = ws + 4 * (size_t)NP;
    float* chig = ws + 5 * (size_t)NP;
    float* nu   = ws + 6 * (size_t)NP;
    float4* PDM = (float4*)(ws + 7 * (size_t)NP);       // 4*NP floats
    float2* AB  = (float2*)(ws + 11 * (size_t)NP);      // 2*NX floats
    float* psum = ws + 43 * (size_t)NP;
    float* pmin = psum + 1024;
    float* ps1  = pmin + 1024;
    float* ps2  = ps1 + 1024;
    float* sc   = ps2 + 1024;   // 16 scalars

    dim3 blk(256);
    k_xschi<<<2048, blk, 0, stream>>>(X, G, Xs, chi, psum, pmin);

    dim3 gplane(NT, Bn);
    k_ssim<<<gplane, blk, 0, stream>>>(Xs, G, muG, vr, taur, chig, nu, ps1, ps2);
    k_red<<<8, blk, 0, stream>>>(psum, pmin, ps1, ps2, sc);
    k_pd<<<(NP / 4) / 256, blk, 0, stream>>>(chi, chig, nu, taur, vr, muG, sc, PDM);

    dim3 gchan(NT, Bn * Cn);
    k_ab<<<gchan, blk, 0, stream>>>(X, G, PDM, AB);
    k_out<<<gchan, blk, 0, stream>>>(AB, G, out);
}

// Round 5
// 137.740 us; speedup vs baseline: 1.4881x; 1.1615x over previous
//
#include <hip/hip_runtime.h>
#include <math.h>

#define EPSC 1e-6f
#define THETAC 1e-3f
#define C1C 1e-4f
#define C2C 9e-4f
#define DEN_EPS 1e-12f

constexpr int Bn = 4, Cn = 16, Hn = 512, Wn = 512;
constexpr int HW = Hn * Wn;          // 262144 = 2^18
constexpr int NP = Bn * HW;          // 1048576
constexpr int TS = 32, RAD = 5, K = 11;
constexpr int HALO = TS + 2 * RAD;   // 42
constexpr int PITCH = 43;            // k_ssim halo pitch
constexpr int HP = 33;               // k_ssim horizontal-sum pitch
constexpr int ASZ = HALO * PITCH;    // 1806
constexpr int HSZ = HALO * HP;       // 1386
constexpr int tiles_x = Wn / TS;     // 16
constexpr int NT = tiles_x * (Hn / TS); // 256

// channel-pass geometry: 48-wide aligned window, pitch 49; swizzled h pitch 32
constexpr int PW = 49;
constexpr int SSZ = HALO * PW;       // 2058
constexpr int HS32 = HALO * 32;      // 1344

__device__ __forceinline__ int refl(int i, int n) {
    if (i < 0) i = -i;
    if (i >= n) i = 2 * n - 2 - i;
    return i;
}

__device__ __forceinline__ int swz_tile(int x) { return (x & 7) * (NT / 8) + (x >> 3); }

__device__ __forceinline__ unsigned int bf16pack(float a, float b) {
    unsigned int ua = __float_as_uint(a), ub = __float_as_uint(b);
    ua += 0x7FFFu + ((ua >> 16) & 1u);
    ub += 0x7FFFu + ((ub >> 16) & 1u);
    return (ua >> 16) | (ub & 0xFFFF0000u);
}
__device__ __forceinline__ float bflo(unsigned int v) { return __uint_as_float(v << 16); }
__device__ __forceinline__ float bfhi(unsigned int v) { return __uint_as_float(v & 0xFFFF0000u); }

// hbox 8-wide chunks into swizzled h (pitch 32): 168 threads
__device__ __forceinline__ void hbox8(const float* s, float* h, int t) {
    if (t < 168) {
        int y = t >> 2, c = t & 3;
        const float* src = s + y * PW + 8 * c + 3;
        int hb = y * 32, xb = 8 * c;
        float acc = src[0];
#pragma unroll
        for (int dx = 1; dx < K; ++dx) acc += src[dx];
        h[hb + ((xb + y) & 31)] = acc;
#pragma unroll
        for (int j = 1; j < 8; ++j) {
            acc += src[j + 10] - src[j - 1];
            h[hb + ((xb + j + y) & 31)] = acc;
        }
    }
}

// vbox from swizzled h: thread owns col x, rows r0..r0+3
__device__ __forceinline__ void vbox32(const float* h, int x, int r0, float m[4]) {
    const float inv = 1.f / 121.f;
    float s = 0.f;
#pragma unroll
    for (int dy = 0; dy < K; ++dy) { int r = r0 + dy; s += h[r * 32 + ((x + r) & 31)]; }
    m[0] = s * inv;
#pragma unroll
    for (int j = 1; j < 4; ++j) {
        int ra = r0 + j + 10, rb = r0 + j - 1;
        s += h[ra * 32 + ((x + ra) & 31)] - h[rb * 32 + ((x + rb) & 31)];
        m[j] = s * inv;
    }
}

// ---------------- K1: merged Xs (channel mean) + chi (+partial reductions) ----------------
__global__ void __launch_bounds__(256) k_xschi(
        const float* __restrict__ X, const float* __restrict__ G,
        float* __restrict__ Xs, float* __restrict__ chi,
        float* __restrict__ psum, float* __restrict__ pmin) {
    int t = threadIdx.x;
    if (blockIdx.x < 1024) {
        constexpr int HW4 = HW / 4;
        int i = blockIdx.x * 256 + t;
        int b = i / HW4, off = i - b * HW4;
        const float4* xp = (const float4*)(X + (size_t)b * Cn * HW) + off;
        float4 s = make_float4(0.f, 0.f, 0.f, 0.f);
#pragma unroll
        for (int c = 0; c < Cn; ++c) {
            float4 v = xp[(size_t)c * HW4];
            s.x += v.x; s.y += v.y; s.z += v.z; s.w += v.w;
        }
        const float sc = 1.0f / Cn;
        s.x *= sc; s.y *= sc; s.z *= sc; s.w *= sc;
        ((float4*)Xs)[i] = s;
        return;
    }
    __shared__ float ssum[256], smin[256];
    int bid = blockIdx.x - 1024;
    int base = bid * 1024;
    float ls = 0.f, lm = 1e30f;
#pragma unroll
    for (int k = 0; k < 4; ++k) {
        int p = base + t + k * 256;
        int off = p & (HW - 1);
        int y = off / Wn, x = off & (Wn - 1);
        float g = G[p];
        float gx = (x < Wn - 1) ? G[p + 1] - g : 0.f;
        float gy = (y < Hn - 1) ? G[p + Wn] - g : 0.f;
        float c = sqrtf(gx * gx + gy * gy + EPSC);
        chi[p] = c;
        ls += c;
        lm = fminf(lm, c);
    }
    ssum[t] = ls; smin[t] = lm;
    __syncthreads();
    for (int s = 128; s > 0; s >>= 1) {
        if (t < s) { ssum[t] += ssum[t + s]; smin[t] = fminf(smin[t], smin[t + s]); }
        __syncthreads();
    }
    if (t == 0) { psum[bid] = ssum[0]; pmin[bid] = smin[0]; }
}

// k_ssim helpers: hbox over 2 planes (x|g), optionally squared; 16-wide chunks
template <bool SQ>
__device__ __forceinline__ void ss_hbox2(const float* arrs, float* hs, int t) {
    if (t < 168) {
        int pl = t / 84, rem = t - pl * 84;
        int y = rem >> 1, xh = (rem & 1) << 4;
        const float* src = arrs + pl * ASZ + y * PITCH + xh;
        float* hd = hs + pl * HSZ + y * HP + xh;
        float v = src[0];
        float s = SQ ? v * v : v;
#pragma unroll
        for (int dx = 1; dx < K; ++dx) { float u = src[dx]; s += SQ ? u * u : u; }
        hd[0] = s;
#pragma unroll
        for (int j = 1; j < 16; ++j) {
            float un = src[j + 10], uo = src[j - 1];
            s += (SQ ? un * un : un) - (SQ ? uo * uo : uo);
            hd[j] = s;
        }
    }
}

__device__ __forceinline__ void ss_vbox(const float* hs, int x, int r0, float m[4]) {
    const float inv_area = 1.f / (float)(K * K);
    int base = r0 * HP + x;
    float s = 0.f;
#pragma unroll
    for (int dy = 0; dy < K; ++dy) s += hs[base + dy * HP];
    m[0] = s * inv_area;
#pragma unroll
    for (int j = 1; j < 4; ++j) {
        s += hs[base + (j + K - 1) * HP] - hs[base + (j - 1) * HP];
        m[j] = s * inv_area;
    }
}

// ---------------- K3: merged ssim r=5 & r=1 + plane outputs + reductions ----------------
__global__ void __launch_bounds__(256) k_ssim(
        const float* __restrict__ Xs, const float* __restrict__ G,
        float* __restrict__ muG, float* __restrict__ varGr, float* __restrict__ taur,
        float* __restrict__ chig, float* __restrict__ nu,
        float* __restrict__ ps1, float* __restrict__ ps2) {
    __shared__ float arrs[2 * ASZ];   // sx, sg halos only
    __shared__ float hs[2 * HSZ];
    float* red1 = hs;                 // aliased after last vbox
    float* red2 = hs + HSZ;
    int t = threadIdx.x;
    int b = blockIdx.y;
    int tile = swz_tile(blockIdx.x);
    int tx0 = (tile % tiles_x) * TS, ty0 = (tile / tiles_x) * TS;
    const float* Xp = Xs + (size_t)b * HW;
    const float* Gp = G + (size_t)b * HW;
    for (int i = t; i < HALO * HALO; i += 256) {
        int ly = i / HALO, lx = i - ly * HALO;
        int gy = refl(ty0 - RAD + ly, Hn), gx = refl(tx0 - RAD + lx, Wn);
        int o = ly * PITCH + lx;
        arrs[o] = Xp[gy * Wn + gx];
        arrs[ASZ + o] = Gp[gy * Wn + gx];
    }
    __syncthreads();

    int x = t & 31, g = t >> 5, r0 = g * 4;
    float acc[5][4];
    // round A: means of x, g
    ss_hbox2<false>(arrs, hs, t);
    __syncthreads();
    ss_vbox(hs, x, r0, acc[0]);
    ss_vbox(hs + HSZ, x, r0, acc[1]);
    __syncthreads();
    // round B: means of x^2, g^2
    ss_hbox2<true>(arrs, hs, t);
    __syncthreads();
    ss_vbox(hs, x, r0, acc[2]);
    ss_vbox(hs + HSZ, x, r0, acc[3]);
    __syncthreads();
    // round C: mean of x*g (8-wide chunks, 168 threads)
    if (t < 168) {
        int y = t >> 2, c = t & 3;
        const float* sx = arrs + y * PITCH + 8 * c;
        const float* sg = arrs + ASZ + y * PITCH + 8 * c;
        float* hd = hs + y * HP + 8 * c;
        float s = sx[0] * sg[0];
#pragma unroll
        for (int dx = 1; dx < K; ++dx) s += sx[dx] * sg[dx];
        hd[0] = s;
#pragma unroll
        for (int j = 1; j < 8; ++j) {
            s += sx[j + 10] * sg[j + 10] - sx[j - 1] * sg[j - 1];
            hd[j] = s;
        }
    }
    __syncthreads();
    ss_vbox(hs, x, r0, acc[4]);

    // r=1 box means for 5 derived planes from sx, sg
    float m1[5][4];
#pragma unroll
    for (int p = 0; p < 5; ++p) {
        float h3[6];
#pragma unroll
        for (int j = 0; j < 6; ++j) {
            int bb = (r0 + 4 + j) * PITCH + (x + 4);
            float s = 0.f;
#pragma unroll
            for (int i = 0; i < 3; ++i) {
                float vx = arrs[bb + i], vg = arrs[ASZ + bb + i];
                float v = (p == 0) ? vx : (p == 1) ? vg : (p == 2) ? vx * vx
                          : (p == 3) ? vg * vg : vx * vg;
                s += v;
            }
            h3[j] = s;
        }
#pragma unroll
        for (int j = 0; j < 4; ++j)
            m1[p][j] = (h3[j] + h3[j + 1] + h3[j + 2]) * (1.f / 9.f);
    }

    float l1 = 0.f, l2 = 0.f;
    float outv[5][4];
#pragma unroll
    for (int j = 0; j < 4; ++j) {
        float mux = acc[0][j], mug = acc[1][j], mxx = acc[2][j], mgg = acc[3][j], mxy = acc[4][j];
        float sx2 = fmaxf(mxx - mux * mux, 0.f);
        float sg2 = fmaxf(mgg - mug * mug, 0.f);
        float sxy = mxy - mux * mug;
        float num = (2.f * mux * mug + C1C) * (2.f * sxy + C2C);
        float den = (mux * mux + mug * mug + C1C) * (sx2 + sg2 + C2C);
        float tr_ = fminf(fmaxf((num / (den + DEN_EPS) + 1.f) * 0.5f, 0.f), 1.f);

        float n0 = m1[0][j], n1 = m1[1][j], n2 = m1[2][j], n3 = m1[3][j], n4 = m1[4][j];
        float sx21 = fmaxf(n2 - n0 * n0, 0.f);
        float sg21 = fmaxf(n3 - n1 * n1, 0.f);
        float sxy1 = n4 - n0 * n1;
        float num1 = (2.f * n0 * n1 + C1C) * (2.f * sxy1 + C2C);
        float den1 = (n0 * n0 + n1 * n1 + C1C) * (sx21 + sg21 + C2C);
        float t1_ = fminf(fmaxf((num1 / (den1 + DEN_EPS) + 1.f) * 0.5f, 0.f), 1.f);

        float chig_ = sqrtf(sg21 + EPSC) * sqrtf(sg2 + EPSC);
        float nu_ = fmaxf(t1_ * tr_, 0.f);
        outv[0][j] = mug; outv[1][j] = sg2; outv[2][j] = tr_;
        outv[3][j] = chig_; outv[4][j] = nu_;
        l1 += 1.f / (chig_ + EPSC);
        l2 += 1.f / (nu_ + THETAC);
    }
#pragma unroll
    for (int j = 0; j < 4; ++j) {
        int gp = b * HW + (ty0 + r0 + j) * Wn + (tx0 + x);
        muG[gp] = outv[0][j];
        varGr[gp] = outv[1][j];
        taur[gp] = outv[2][j];
        chig[gp] = outv[3][j];
        nu[gp] = outv[4][j];
    }
    __syncthreads();   // hs reads done; safe to alias red1/red2
    red1[t] = l1; red2[t] = l2;
    __syncthreads();
    for (int s = 128; s > 0; s >>= 1) {
        if (t < s) { red1[t] += red1[t + s]; red2[t] += red2[t + s]; }
        __syncthreads();
    }
    if (t == 0) {
        ps1[b * NT + blockIdx.x] = red1[0];
        ps2[b * NT + blockIdx.x] = red2[0];
    }
}

// ---------------- K red: merged chired + nured ----------------
__global__ void __launch_bounds__(256) k_red(
        const float* __restrict__ psum, const float* __restrict__ pmin,
        const float* __restrict__ s1, const float* __restrict__ s2,
        float* __restrict__ sc) {
    __shared__ float a1[256], a2[256];
    int t = threadIdx.x;
    if (blockIdx.x < 4) {
        int b = blockIdx.x;
        a1[t] = psum[b * 256 + t];
        a2[t] = pmin[b * 256 + t];
        __syncthreads();
        for (int s = 128; s > 0; s >>= 1) {
            if (t < s) { a1[t] += a1[t + s]; a2[t] = fminf(a2[t], a2[t + s]); }
            __syncthreads();
        }
        if (t == 0) {
            float mu = a1[0] / (float)HW;
            sc[b] = mu;
            sc[4 + b] = fmaxf(mu - a2[0], EPSC);
        }
    } else {
        int b = blockIdx.x - 4;
        a1[t] = s1[b * 256 + t];
        a2[t] = s2[b * 256 + t];
        __syncthreads();
        for (int s = 128; s > 0; s >>= 1) {
            if (t < s) { a1[t] += a1[t + s]; a2[t] += a2[t + s]; }
            __syncthreads();
        }
        if (t == 0) {
            sc[8 + b] = a1[0] / (float)HW;
            sc[12 + b] = a2[0] / (float)HW;
        }
    }
}

// ---------------- K4: per-pixel packed (P, D, muG) plane, 4-wide ----------------
__global__ void __launch_bounds__(256) k_pd(
        const float* __restrict__ chi, const float* __restrict__ chig,
        const float* __restrict__ nu, const float* __restrict__ taur,
        const float* __restrict__ vr, const float* __restrict__ muG,
        const float* __restrict__ sc, float4* __restrict__ PDM) {
    int i = blockIdx.x * 256 + threadIdx.x;   // i < NP/4
    int p0 = i * 4;
    int b = p0 >> 18;
    float mu = sc[b], eta = sc[4 + b], imc = sc[8 + b], imn = sc[12 + b];
    float4 c4 = ((const float4*)chi)[i];
    float4 cg4 = ((const float4*)chig)[i];
    float4 nu4 = ((const float4*)nu)[i];
    float4 tr4 = ((const float4*)taur)[i];
    float4 vr4 = ((const float4*)vr)[i];
    float4 mg4 = ((const float4*)muG)[i];
    float cc[4] = {c4.x, c4.y, c4.z, c4.w};
    float gg[4] = {cg4.x, cg4.y, cg4.z, cg4.w};
    float nn[4] = {nu4.x, nu4.y, nu4.z, nu4.w};
    float tt[4] = {tr4.x, tr4.y, tr4.z, tr4.w};
    float vv[4] = {vr4.x, vr4.y, vr4.z, vr4.w};
    float mm[4] = {mg4.x, mg4.y, mg4.z, mg4.w};
#pragma unroll
    for (int j = 0; j < 4; ++j) {
        float gamma = 1.f / (1.f + expf(-eta * (cc[j] - mu)));
        float GG = (gg[j] + EPSC) * imc;
        float w_e = 1.0f / (GG + EPSC);
        float GS = (nn[j] + THETAC) * imn;
        float w_s = gamma / (GS + EPSC);
        float P = w_e * gamma + w_s * tt[j];
        float D = vv[j] + EPSC + w_e + w_s + EPSC;
        PDM[p0 + j] = make_float4(P, D, mm[j], 0.f);
    }
}

// ---------------- K5: per-channel a,b (single swizzled h; bf16 AB out) ----------------
__global__ void __launch_bounds__(256) k_ab(
        const float* __restrict__ X, const float* __restrict__ G,
        const float4* __restrict__ PDM, unsigned int* __restrict__ AB) {
    __shared__ float s0[SSZ], s1[SSZ];   // X, X*G (48-wide window, pitch 49)
    __shared__ float h[HS32];
    int t = threadIdx.x;
    int pc = blockIdx.y, b = pc >> 4;
    int tile = swz_tile(blockIdx.x);
    int tx0 = (tile & 15) * TS, ty0 = (tile >> 4) * TS;
    int x = t & 31, wg = t >> 5, r0 = wg * 4;
    // prefetch epilogue operands (latency hides under halo load)
    const float4* Pp = PDM + (size_t)b * HW;
    int pbase = (ty0 + r0) * Wn + tx0 + x;
    float4 pdm0 = Pp[pbase];
    float4 pdm1 = Pp[pbase + Wn];
    float4 pdm2 = Pp[pbase + 2 * Wn];
    float4 pdm3 = Pp[pbase + 3 * Wn];

    const float* Xp = X + (size_t)pc * HW;
    const float* Gp = G + (size_t)b * HW;
    bool interior = (tx0 >= 32 && tx0 <= 448 && ty0 >= 32 && ty0 <= 448);
    if (interior) {
        int base = (ty0 - 5) * Wn + (tx0 - 8);
        for (int u = t; u < HALO * 12; u += 256) {     // 504 float4 units
            int ly = u / 12, k = u - ly * 12;
            int gi = base + ly * Wn + 4 * k;
            float4 xv = *(const float4*)(Xp + gi);
            float4 gv = *(const float4*)(Gp + gi);
            int o = ly * PW + 4 * k;
            s0[o] = xv.x; s0[o + 1] = xv.y; s0[o + 2] = xv.z; s0[o + 3] = xv.w;
            s1[o] = xv.x * gv.x; s1[o + 1] = xv.y * gv.y;
            s1[o + 2] = xv.z * gv.z; s1[o + 3] = xv.w * gv.w;
        }
    } else {
        for (int u = t; u < HALO * 48; u += 256) {
            int ly = u / 48, l = u - ly * 48;
            int gy = refl(ty0 - 5 + ly, Hn), gx = refl(tx0 - 8 + l, Wn);
            float xv = Xp[gy * Wn + gx], gv = Gp[gy * Wn + gx];
            s0[ly * PW + l] = xv;
            s1[ly * PW + l] = xv * gv;
        }
    }
    __syncthreads();
    hbox8(s0, h, t);
    __syncthreads();
    float mx[4];
    vbox32(h, x, r0, mx);
    __syncthreads();
    hbox8(s1, h, t);
    __syncthreads();
    float mxg[4];
    vbox32(h, x, r0, mxg);

    unsigned int* Ap = AB + (size_t)pc * HW;
    float4 pdm[4] = {pdm0, pdm1, pdm2, pdm3};
#pragma unroll
    for (int j = 0; j < 4; ++j) {
        float a = (mxg[j] - pdm[j].z * mx[j] + pdm[j].x) / pdm[j].y;
        float bb = mx[j] - a * pdm[j].z;
        Ap[pbase + j * Wn] = bf16pack(a, bb);
    }
}

// ---------------- K6: out = box11(a)*G + box11(b) ----------------
__global__ void __launch_bounds__(256) k_out(
        const unsigned int* __restrict__ AB, const float* __restrict__ G,
        float* __restrict__ out) {
    __shared__ float s0[SSZ], s1[SSZ];   // a, b
    __shared__ float h[HS32];
    int t = threadIdx.x;
    int pc = blockIdx.y, b = pc >> 4;
    int tile = swz_tile(blockIdx.x);
    int tx0 = (tile & 15) * TS, ty0 = (tile >> 4) * TS;
    int x = t & 31, wg = t >> 5, r0 = wg * 4;
    // prefetch G for epilogue
    const float* Gp = G + (size_t)b * HW;
    int pbase = (ty0 + r0) * Wn + tx0 + x;
    float g0 = Gp[pbase], g1 = Gp[pbase + Wn], g2 = Gp[pbase + 2 * Wn], g3 = Gp[pbase + 3 * Wn];

    const unsigned int* Ap = AB + (size_t)pc * HW;
    bool interior = (tx0 >= 32 && tx0 <= 448 && ty0 >= 32 && ty0 <= 448);
    if (interior) {
        int base = (ty0 - 5) * Wn + (tx0 - 8);
        for (int u = t; u < HALO * 12; u += 256) {     // 504 uint4 units
            int ly = u / 12, k = u - ly * 12;
            uint4 v = *(const uint4*)(Ap + base + ly * Wn + 4 * k);
            int o = ly * PW + 4 * k;
            s0[o] = bflo(v.x); s1[o] = bfhi(v.x);
            s0[o + 1] = bflo(v.y); s1[o + 1] = bfhi(v.y);
            s0[o + 2] = bflo(v.z); s1[o + 2] = bfhi(v.z);
            s0[o + 3] = bflo(v.w); s1[o + 3] = bfhi(v.w);
        }
    } else {
        for (int u = t; u < HALO * 48; u += 256) {
            int ly = u / 48, l = u - ly * 48;
            int gy = refl(ty0 - 5 + ly, Hn), gx = refl(tx0 - 8 + l, Wn);
            unsigned int v = Ap[gy * Wn + gx];
            s0[ly * PW + l] = bflo(v);
            s1[ly * PW + l] = bfhi(v);
        }
    }
    __syncthreads();
    hbox8(s0, h, t);
    __syncthreads();
    float ma[4];
    vbox32(h, x, r0, ma);
    __syncthreads();
    hbox8(s1, h, t);
    __syncthreads();
    float mb[4];
    vbox32(h, x, r0, mb);

    float* op = out + (size_t)pc * HW;
    float gv[4] = {g0, g1, g2, g3};
#pragma unroll
    for (int j = 0; j < 4; ++j)
        op[pbase + j * Wn] = ma[j] * gv[j] + mb[j];
}

extern "C" void kernel_launch(void* const* d_in, const int* in_sizes, int n_in,
                              void* d_out, int out_size, void* d_ws, size_t ws_size,
                              hipStream_t stream) {
    const float* X = (const float*)d_in[0];
    const float* G = (const float*)d_in[1];
    float* out = (float*)d_out;
    float* ws = (float*)d_ws;

    float* Xs   = ws + 0 * (size_t)NP;
    float* chi  = ws + 1 * (size_t)NP;
    float* taur = ws + 2 * (size_t)NP;
    float* vr   = ws + 3 * (size_t)NP;
    float* muG  = ws + 4 * (size_t)NP;
    float* chig = ws + 5 * (size_t)NP;
    float* nu   = ws + 6 * (size_t)NP;
    float4* PDM = (float4*)(ws + 7 * (size_t)NP);            // 4*NP floats
    unsigned int* AB = (unsigned int*)(ws + 11 * (size_t)NP); // NX uints
    float* psum = ws + 43 * (size_t)NP;
    float* pmin = psum + 1024;
    float* ps1  = pmin + 1024;
    float* ps2  = ps1 + 1024;
    float* sc   = ps2 + 1024;   // 16 scalars

    dim3 blk(256);
    k_xschi<<<2048, blk, 0, stream>>>(X, G, Xs, chi, psum, pmin);

    dim3 gplane(NT, Bn);
    k_ssim<<<gplane, blk, 0, stream>>>(Xs, G, muG, vr, taur, chig, nu, ps1, ps2);
    k_red<<<8, blk, 0, stream>>>(psum, pmin, ps1, ps2, sc);
    k_pd<<<(NP / 4) / 256, blk, 0, stream>>>(chi, chig, nu, taur, vr, muG, sc, PDM);

    dim3 gchan(NT, Bn * Cn);
    k_ab<<<gchan, blk, 0, stream>>>(X, G, PDM, AB);
    k_out<<<gchan, blk, 0, stream>>>(AB, G, out);
}

// Round 6
// 126.531 us; speedup vs baseline: 1.6200x; 1.0886x over previous
//
#include <hip/hip_runtime.h>
#include <math.h>

#define EPSC 1e-6f
#define THETAC 1e-3f
#define C1C 1e-4f
#define C2C 9e-4f
#define DEN_EPS 1e-12f

constexpr int Bn = 4, Cn = 16, Hn = 512, Wn = 512;
constexpr int HW = Hn * Wn;          // 262144 = 2^18
constexpr int NP = Bn * HW;          // 1048576
constexpr int TS = 32, RAD = 5, K = 11;
constexpr int HALO = TS + 2 * RAD;   // 42
constexpr int PITCH = 43;            // k_ssim halo pitch
constexpr int HP = 33;               // horizontal-sum pitch (linear, conflict-free)
constexpr int ASZ = HALO * PITCH;    // 1806
constexpr int HSZ = HALO * HP;       // 1386
constexpr int tiles_x = Wn / TS;     // 16
constexpr int NT = tiles_x * (Hn / TS); // 256

// channel-pass geometry: 48-wide aligned window, pitch 49
constexpr int PW = 49;
constexpr int SSZ = HALO * PW;       // 2058

__device__ __forceinline__ int refl(int i, int n) {
    if (i < 0) i = -i;
    if (i >= n) i = 2 * n - 2 - i;
    return i;
}

__device__ __forceinline__ int swz_tile(int x) { return (x & 7) * (NT / 8) + (x >> 3); }

__device__ __forceinline__ unsigned int bf16pack(float a, float b) {
    unsigned int ua = __float_as_uint(a), ub = __float_as_uint(b);
    ua += 0x7FFFu + ((ua >> 16) & 1u);
    ub += 0x7FFFu + ((ub >> 16) & 1u);
    return (ua >> 16) | (ub & 0xFFFF0000u);
}
__device__ __forceinline__ float bflo(unsigned int v) { return __uint_as_float(v << 16); }
__device__ __forceinline__ float bfhi(unsigned int v) { return __uint_as_float(v & 0xFFFF0000u); }

// hbox 8-wide chunks into linear pitch-33 h: 168 threads
// writes h[y*33 + 8c + j]: same-(c,j) lanes differ in y -> distinct banks (pitch 33)
__device__ __forceinline__ void hboxp(const float* s, float* h, int t) {
    if (t < 168) {
        int y = t >> 2, c = t & 3;
        const float* src = s + y * PW + 8 * c + 3;
        float* dst = h + y * HP + 8 * c;
        float acc = src[0];
#pragma unroll
        for (int dx = 1; dx < K; ++dx) acc += src[dx];
        dst[0] = acc;
#pragma unroll
        for (int j = 1; j < 8; ++j) {
            acc += src[j + 10] - src[j - 1];
            dst[j] = acc;
        }
    }
}

// vbox from linear h: thread owns col x, rows r0..r0+3; taps are
// immediate-offset ds_read_b32 off one base (dy*33*4 folds into offset field)
__device__ __forceinline__ void vboxp(const float* h, int x, int r0, float m[4]) {
    const float inv = 1.f / 121.f;
    const float* hb = h + r0 * HP + x;
    float s = hb[0];
#pragma unroll
    for (int dy = 1; dy < K; ++dy) s += hb[dy * HP];
    m[0] = s * inv;
#pragma unroll
    for (int j = 1; j < 4; ++j) {
        s += hb[(j + 10) * HP] - hb[(j - 1) * HP];
        m[j] = s * inv;
    }
}

// ---------------- K1: merged Xs (channel mean) + chi (+partial reductions) ----------------
__global__ void __launch_bounds__(256) k_xschi(
        const float* __restrict__ X, const float* __restrict__ G,
        float* __restrict__ Xs, float* __restrict__ chi,
        float* __restrict__ psum, float* __restrict__ pmin) {
    int t = threadIdx.x;
    if (blockIdx.x < 1024) {
        constexpr int HW4 = HW / 4;
        int i = blockIdx.x * 256 + t;
        int b = i / HW4, off = i - b * HW4;
        const float4* xp = (const float4*)(X + (size_t)b * Cn * HW) + off;
        float4 s = make_float4(0.f, 0.f, 0.f, 0.f);
#pragma unroll
        for (int c = 0; c < Cn; ++c) {
            float4 v = xp[(size_t)c * HW4];
            s.x += v.x; s.y += v.y; s.z += v.z; s.w += v.w;
        }
        const float sc = 1.0f / Cn;
        s.x *= sc; s.y *= sc; s.z *= sc; s.w *= sc;
        ((float4*)Xs)[i] = s;
        return;
    }
    __shared__ float ssum[256], smin[256];
    int bid = blockIdx.x - 1024;
    int base = bid * 1024;
    float ls = 0.f, lm = 1e30f;
#pragma unroll
    for (int k = 0; k < 4; ++k) {
        int p = base + t + k * 256;
        int off = p & (HW - 1);
        int y = off / Wn, x = off & (Wn - 1);
        float g = G[p];
        float gx = (x < Wn - 1) ? G[p + 1] - g : 0.f;
        float gy = (y < Hn - 1) ? G[p + Wn] - g : 0.f;
        float c = sqrtf(gx * gx + gy * gy + EPSC);
        chi[p] = c;
        ls += c;
        lm = fminf(lm, c);
    }
    ssum[t] = ls; smin[t] = lm;
    __syncthreads();
    for (int s = 128; s > 0; s >>= 1) {
        if (t < s) { ssum[t] += ssum[t + s]; smin[t] = fminf(smin[t], smin[t + s]); }
        __syncthreads();
    }
    if (t == 0) { psum[bid] = ssum[0]; pmin[bid] = smin[0]; }
}

// k_ssim helpers: hbox over 2 planes (x|g), optionally squared; 16-wide chunks
template <bool SQ>
__device__ __forceinline__ void ss_hbox2(const float* arrs, float* hs, int t) {
    if (t < 168) {
        int pl = t / 84, rem = t - pl * 84;
        int y = rem >> 1, xh = (rem & 1) << 4;
        const float* src = arrs + pl * ASZ + y * PITCH + xh;
        float* hd = hs + pl * HSZ + y * HP + xh;
        float v = src[0];
        float s = SQ ? v * v : v;
#pragma unroll
        for (int dx = 1; dx < K; ++dx) { float u = src[dx]; s += SQ ? u * u : u; }
        hd[0] = s;
#pragma unroll
        for (int j = 1; j < 16; ++j) {
            float un = src[j + 10], uo = src[j - 1];
            s += (SQ ? un * un : un) - (SQ ? uo * uo : uo);
            hd[j] = s;
        }
    }
}

__device__ __forceinline__ void ss_vbox(const float* hs, int x, int r0, float m[4]) {
    const float inv_area = 1.f / (float)(K * K);
    const float* hb = hs + r0 * HP + x;
    float s = hb[0];
#pragma unroll
    for (int dy = 1; dy < K; ++dy) s += hb[dy * HP];
    m[0] = s * inv_area;
#pragma unroll
    for (int j = 1; j < 4; ++j) {
        s += hb[(j + 10) * HP] - hb[(j - 1) * HP];
        m[j] = s * inv_area;
    }
}

// ---------------- K3: merged ssim r=5 & r=1 + plane outputs + reductions ----------------
__global__ void __launch_bounds__(256) k_ssim(
        const float* __restrict__ Xs, const float* __restrict__ G,
        float* __restrict__ muG, float* __restrict__ varGr, float* __restrict__ taur,
        float* __restrict__ chig, float* __restrict__ nu,
        float* __restrict__ ps1, float* __restrict__ ps2) {
    __shared__ float arrs[2 * ASZ];   // sx, sg halos only
    __shared__ float hs[2 * HSZ];
    float* red1 = hs;                 // aliased after last vbox
    float* red2 = hs + HSZ;
    int t = threadIdx.x;
    int b = blockIdx.y;
    int tile = swz_tile(blockIdx.x);
    int tx0 = (tile % tiles_x) * TS, ty0 = (tile / tiles_x) * TS;
    const float* Xp = Xs + (size_t)b * HW;
    const float* Gp = G + (size_t)b * HW;
    for (int i = t; i < HALO * HALO; i += 256) {
        int ly = i / HALO, lx = i - ly * HALO;
        int gy = refl(ty0 - RAD + ly, Hn), gx = refl(tx0 - RAD + lx, Wn);
        int o = ly * PITCH + lx;
        arrs[o] = Xp[gy * Wn + gx];
        arrs[ASZ + o] = Gp[gy * Wn + gx];
    }
    __syncthreads();

    int x = t & 31, g = t >> 5, r0 = g * 4;
    float acc[5][4];
    // round A: means of x, g
    ss_hbox2<false>(arrs, hs, t);
    __syncthreads();
    ss_vbox(hs, x, r0, acc[0]);
    ss_vbox(hs + HSZ, x, r0, acc[1]);
    __syncthreads();
    // round B: means of x^2, g^2
    ss_hbox2<true>(arrs, hs, t);
    __syncthreads();
    ss_vbox(hs, x, r0, acc[2]);
    ss_vbox(hs + HSZ, x, r0, acc[3]);
    __syncthreads();
    // round C: mean of x*g (8-wide chunks, 168 threads)
    if (t < 168) {
        int y = t >> 2, c = t & 3;
        const float* sx = arrs + y * PITCH + 8 * c;
        const float* sg = arrs + ASZ + y * PITCH + 8 * c;
        float* hd = hs + y * HP + 8 * c;
        float s = sx[0] * sg[0];
#pragma unroll
        for (int dx = 1; dx < K; ++dx) s += sx[dx] * sg[dx];
        hd[0] = s;
#pragma unroll
        for (int j = 1; j < 8; ++j) {
            s += sx[j + 10] * sg[j + 10] - sx[j - 1] * sg[j - 1];
            hd[j] = s;
        }
    }
    __syncthreads();
    ss_vbox(hs, x, r0, acc[4]);

    // r=1 box means for 5 derived planes from sx, sg
    float m1[5][4];
#pragma unroll
    for (int p = 0; p < 5; ++p) {
        float h3[6];
#pragma unroll
        for (int j = 0; j < 6; ++j) {
            int bb = (r0 + 4 + j) * PITCH + (x + 4);
            float s = 0.f;
#pragma unroll
            for (int i = 0; i < 3; ++i) {
                float vx = arrs[bb + i], vg = arrs[ASZ + bb + i];
                float v = (p == 0) ? vx : (p == 1) ? vg : (p == 2) ? vx * vx
                          : (p == 3) ? vg * vg : vx * vg;
                s += v;
            }
            h3[j] = s;
        }
#pragma unroll
        for (int j = 0; j < 4; ++j)
            m1[p][j] = (h3[j] + h3[j + 1] + h3[j + 2]) * (1.f / 9.f);
    }

    float l1 = 0.f, l2 = 0.f;
    float outv[5][4];
#pragma unroll
    for (int j = 0; j < 4; ++j) {
        float mux = acc[0][j], mug = acc[1][j], mxx = acc[2][j], mgg = acc[3][j], mxy = acc[4][j];
        float sx2 = fmaxf(mxx - mux * mux, 0.f);
        float sg2 = fmaxf(mgg - mug * mug, 0.f);
        float sxy = mxy - mux * mug;
        float num = (2.f * mux * mug + C1C) * (2.f * sxy + C2C);
        float den = (mux * mux + mug * mug + C1C) * (sx2 + sg2 + C2C);
        float tr_ = fminf(fmaxf((num / (den + DEN_EPS) + 1.f) * 0.5f, 0.f), 1.f);

        float n0 = m1[0][j], n1 = m1[1][j], n2 = m1[2][j], n3 = m1[3][j], n4 = m1[4][j];
        float sx21 = fmaxf(n2 - n0 * n0, 0.f);
        float sg21 = fmaxf(n3 - n1 * n1, 0.f);
        float sxy1 = n4 - n0 * n1;
        float num1 = (2.f * n0 * n1 + C1C) * (2.f * sxy1 + C2C);
        float den1 = (n0 * n0 + n1 * n1 + C1C) * (sx21 + sg21 + C2C);
        float t1_ = fminf(fmaxf((num1 / (den1 + DEN_EPS) + 1.f) * 0.5f, 0.f), 1.f);

        float chig_ = sqrtf(sg21 + EPSC) * sqrtf(sg2 + EPSC);
        float nu_ = fmaxf(t1_ * tr_, 0.f);
        outv[0][j] = mug; outv[1][j] = sg2; outv[2][j] = tr_;
        outv[3][j] = chig_; outv[4][j] = nu_;
        l1 += 1.f / (chig_ + EPSC);
        l2 += 1.f / (nu_ + THETAC);
    }
#pragma unroll
    for (int j = 0; j < 4; ++j) {
        int gp = b * HW + (ty0 + r0 + j) * Wn + (tx0 + x);
        muG[gp] = outv[0][j];
        varGr[gp] = outv[1][j];
        taur[gp] = outv[2][j];
        chig[gp] = outv[3][j];
        nu[gp] = outv[4][j];
    }
    __syncthreads();   // hs reads done; safe to alias red1/red2
    red1[t] = l1; red2[t] = l2;
    __syncthreads();
    for (int s = 128; s > 0; s >>= 1) {
        if (t < s) { red1[t] += red1[t + s]; red2[t] += red2[t + s]; }
        __syncthreads();
    }
    if (t == 0) {
        ps1[b * NT + blockIdx.x] = red1[0];
        ps2[b * NT + blockIdx.x] = red2[0];
    }
}

// ---------------- K red: merged chired + nured ----------------
__global__ void __launch_bounds__(256) k_red(
        const float* __restrict__ psum, const float* __restrict__ pmin,
        const float* __restrict__ s1, const float* __restrict__ s2,
        float* __restrict__ sc) {
    __shared__ float a1[256], a2[256];
    int t = threadIdx.x;
    if (blockIdx.x < 4) {
        int b = blockIdx.x;
        a1[t] = psum[b * 256 + t];
        a2[t] = pmin[b * 256 + t];
        __syncthreads();
        for (int s = 128; s > 0; s >>= 1) {
            if (t < s) { a1[t] += a1[t + s]; a2[t] = fminf(a2[t], a2[t + s]); }
            __syncthreads();
        }
        if (t == 0) {
            float mu = a1[0] / (float)HW;
            sc[b] = mu;
            sc[4 + b] = fmaxf(mu - a2[0], EPSC);
        }
    } else {
        int b = blockIdx.x - 4;
        a1[t] = s1[b * 256 + t];
        a2[t] = s2[b * 256 + t];
        __syncthreads();
        for (int s = 128; s > 0; s >>= 1) {
            if (t < s) { a1[t] += a1[t + s]; a2[t] += a2[t + s]; }
            __syncthreads();
        }
        if (t == 0) {
            sc[8 + b] = a1[0] / (float)HW;
            sc[12 + b] = a2[0] / (float)HW;
        }
    }
}

// ---------------- K4: per-pixel packed (P, D, muG) plane, 4-wide ----------------
__global__ void __launch_bounds__(256) k_pd(
        const float* __restrict__ chi, const float* __restrict__ chig,
        const float* __restrict__ nu, const float* __restrict__ taur,
        const float* __restrict__ vr, const float* __restrict__ muG,
        const float* __restrict__ sc, float4* __restrict__ PDM) {
    int i = blockIdx.x * 256 + threadIdx.x;   // i < NP/4
    int p0 = i * 4;
    int b = p0 >> 18;
    float mu = sc[b], eta = sc[4 + b], imc = sc[8 + b], imn = sc[12 + b];
    float4 c4 = ((const float4*)chi)[i];
    float4 cg4 = ((const float4*)chig)[i];
    float4 nu4 = ((const float4*)nu)[i];
    float4 tr4 = ((const float4*)taur)[i];
    float4 vr4 = ((const float4*)vr)[i];
    float4 mg4 = ((const float4*)muG)[i];
    float cc[4] = {c4.x, c4.y, c4.z, c4.w};
    float gg[4] = {cg4.x, cg4.y, cg4.z, cg4.w};
    float nn[4] = {nu4.x, nu4.y, nu4.z, nu4.w};
    float tt[4] = {tr4.x, tr4.y, tr4.z, tr4.w};
    float vv[4] = {vr4.x, vr4.y, vr4.z, vr4.w};
    float mm[4] = {mg4.x, mg4.y, mg4.z, mg4.w};
#pragma unroll
    for (int j = 0; j < 4; ++j) {
        float gamma = 1.f / (1.f + expf(-eta * (cc[j] - mu)));
        float GG = (gg[j] + EPSC) * imc;
        float w_e = 1.0f / (GG + EPSC);
        float GS = (nn[j] + THETAC) * imn;
        float w_s = gamma / (GS + EPSC);
        float P = w_e * gamma + w_s * tt[j];
        float D = vv[j] + EPSC + w_e + w_s + EPSC;
        PDM[p0 + j] = make_float4(P, D, mm[j], 0.f);
    }
}

// ---------------- K5: per-channel a,b (linear h; bf16 AB out) ----------------
__global__ void __launch_bounds__(256) k_ab(
        const float* __restrict__ X, const float* __restrict__ G,
        const float4* __restrict__ PDM, unsigned int* __restrict__ AB) {
    __shared__ float s0[SSZ], s1[SSZ];   // X, X*G (48-wide window, pitch 49)
    __shared__ float h[HSZ];
    int t = threadIdx.x;
    int pc = blockIdx.y, b = pc >> 4;
    int tile = swz_tile(blockIdx.x);
    int tx0 = (tile & 15) * TS, ty0 = (tile >> 4) * TS;
    int x = t & 31, wg = t >> 5, r0 = wg * 4;
    // prefetch epilogue operands (latency hides under halo load)
    const float4* Pp = PDM + (size_t)b * HW;
    int pbase = (ty0 + r0) * Wn + tx0 + x;
    float4 pdm0 = Pp[pbase];
    float4 pdm1 = Pp[pbase + Wn];
    float4 pdm2 = Pp[pbase + 2 * Wn];
    float4 pdm3 = Pp[pbase + 3 * Wn];

    const float* Xp = X + (size_t)pc * HW;
    const float* Gp = G + (size_t)b * HW;
    bool interior = (tx0 >= 32 && tx0 <= 448 && ty0 >= 32 && ty0 <= 448);
    if (interior) {
        int base = (ty0 - 5) * Wn + (tx0 - 8);
        for (int u = t; u < HALO * 12; u += 256) {     // 504 float4 units
            int ly = u / 12, k = u - ly * 12;
            int gi = base + ly * Wn + 4 * k;
            float4 xv = *(const float4*)(Xp + gi);
            float4 gv = *(const float4*)(Gp + gi);
            int o = ly * PW + 4 * k;
            s0[o] = xv.x; s0[o + 1] = xv.y; s0[o + 2] = xv.z; s0[o + 3] = xv.w;
            s1[o] = xv.x * gv.x; s1[o + 1] = xv.y * gv.y;
            s1[o + 2] = xv.z * gv.z; s1[o + 3] = xv.w * gv.w;
        }
    } else {
        for (int u = t; u < HALO * 48; u += 256) {
            int ly = u / 48, l = u - ly * 48;
            int gy = refl(ty0 - 5 + ly, Hn), gx = refl(tx0 - 8 + l, Wn);
            float xv = Xp[gy * Wn + gx], gv = Gp[gy * Wn + gx];
            s0[ly * PW + l] = xv;
            s1[ly * PW + l] = xv * gv;
        }
    }
    __syncthreads();
    hboxp(s0, h, t);
    __syncthreads();
    float mx[4];
    vboxp(h, x, r0, mx);
    __syncthreads();
    hboxp(s1, h, t);
    __syncthreads();
    float mxg[4];
    vboxp(h, x, r0, mxg);

    unsigned int* Ap = AB + (size_t)pc * HW;
    float4 pdm[4] = {pdm0, pdm1, pdm2, pdm3};
#pragma unroll
    for (int j = 0; j < 4; ++j) {
        float a = (mxg[j] - pdm[j].z * mx[j] + pdm[j].x) / pdm[j].y;
        float bb = mx[j] - a * pdm[j].z;
        Ap[pbase + j * Wn] = bf16pack(a, bb);
    }
}

// ---------------- K6: out = box11(a)*G + box11(b) ----------------
__global__ void __launch_bounds__(256) k_out(
        const unsigned int* __restrict__ AB, const float* __restrict__ G,
        float* __restrict__ out) {
    __shared__ float s0[SSZ], s1[SSZ];   // a, b
    __shared__ float h[HSZ];
    int t = threadIdx.x;
    int pc = blockIdx.y, b = pc >> 4;
    int tile = swz_tile(blockIdx.x);
    int tx0 = (tile & 15) * TS, ty0 = (tile >> 4) * TS;
    int x = t & 31, wg = t >> 5, r0 = wg * 4;
    // prefetch G for epilogue
    const float* Gp = G + (size_t)b * HW;
    int pbase = (ty0 + r0) * Wn + tx0 + x;
    float g0 = Gp[pbase], g1 = Gp[pbase + Wn], g2 = Gp[pbase + 2 * Wn], g3 = Gp[pbase + 3 * Wn];

    const unsigned int* Ap = AB + (size_t)pc * HW;
    bool interior = (tx0 >= 32 && tx0 <= 448 && ty0 >= 32 && ty0 <= 448);
    if (interior) {
        int base = (ty0 - 5) * Wn + (tx0 - 8);
        for (int u = t; u < HALO * 12; u += 256) {     // 504 uint4 units
            int ly = u / 12, k = u - ly * 12;
            uint4 v = *(const uint4*)(Ap + base + ly * Wn + 4 * k);
            int o = ly * PW + 4 * k;
            s0[o] = bflo(v.x); s1[o] = bfhi(v.x);
            s0[o + 1] = bflo(v.y); s1[o + 1] = bfhi(v.y);
            s0[o + 2] = bflo(v.z); s1[o + 2] = bfhi(v.z);
            s0[o + 3] = bflo(v.w); s1[o + 3] = bfhi(v.w);
        }
    } else {
        for (int u = t; u < HALO * 48; u += 256) {
            int ly = u / 48, l = u - ly * 48;
            int gy = refl(ty0 - 5 + ly, Hn), gx = refl(tx0 - 8 + l, Wn);
            unsigned int v = Ap[gy * Wn + gx];
            s0[ly * PW + l] = bflo(v);
            s1[ly * PW + l] = bfhi(v);
        }
    }
    __syncthreads();
    hboxp(s0, h, t);
    __syncthreads();
    float ma[4];
    vboxp(h, x, r0, ma);
    __syncthreads();
    hboxp(s1, h, t);
    __syncthreads();
    float mb[4];
    vboxp(h, x, r0, mb);

    float* op = out + (size_t)pc * HW;
    float gv[4] = {g0, g1, g2, g3};
#pragma unroll
    for (int j = 0; j < 4; ++j)
        op[pbase + j * Wn] = ma[j] * gv[j] + mb[j];
}

extern "C" void kernel_launch(void* const* d_in, const int* in_sizes, int n_in,
                              void* d_out, int out_size, void* d_ws, size_t ws_size,
                              hipStream_t stream) {
    const float* X = (const float*)d_in[0];
    const float* G = (const float*)d_in[1];
    float* out = (float*)d_out;
    float* ws = (float*)d_ws;

    float* Xs   = ws + 0 * (size_t)NP;
    float* chi  = ws + 1 * (size_t)NP;
    float* taur = ws + 2 * (size_t)NP;
    float* vr   = ws + 3 * (size_t)NP;
    float* muG  = ws + 4 * (size_t)NP;
    float* chig = ws + 5 * (size_t)NP;
    float* nu   = ws + 6 * (size_t)NP;
    float4* PDM = (float4*)(ws + 7 * (size_t)NP);            // 4*NP floats
    unsigned int* AB = (unsigned int*)(ws + 11 * (size_t)NP); // NX uints
    float* psum = ws + 43 * (size_t)NP;
    float* pmin = psum + 1024;
    float* ps1  = pmin + 1024;
    float* ps2  = ps1 + 1024;
    float* sc   = ps2 + 1024;   // 16 scalars

    dim3 blk(256);
    k_xschi<<<2048, blk, 0, stream>>>(X, G, Xs, chi, psum, pmin);

    dim3 gplane(NT, Bn);
    k_ssim<<<gplane, blk, 0, stream>>>(Xs, G, muG, vr, taur, chig, nu, ps1, ps2);
    k_red<<<8, blk, 0, stream>>>(psum, pmin, ps1, ps2, sc);
    k_pd<<<(NP / 4) / 256, blk, 0, stream>>>(chi, chig, nu, taur, vr, muG, sc, PDM);

    dim3 gchan(NT, Bn * Cn);
    k_ab<<<gchan, blk, 0, stream>>>(X, G, PDM, AB);
    k_out<<<gchan, blk, 0, stream>>>(AB, G, out);
}